// Round 5
// baseline (27.017 us; speedup 1.0000x reference)
//
#include <hip/hip_runtime.h>
#include <math.h>

#define NB 32
#define NH 128
#define NW 128
#define NC 3
#define NF 2
#define NQ 9
#define NL 2
#define I0 126
#define I1 126
#define NGJ 14                        // 126 / 9 groups along j
#define NGROUPS (NB * I0 * NGJ)       // 56,448 pixel-groups of 9
#define GTHREADS (NGROUPS * 18)       // 1,016,064 = 3969 * 256 exactly
#define INV2PI 0.15915494309189535f

struct f3 { float x, y, z; };         // 4B-aligned triple -> dwordx3

__global__ __launch_bounds__(256) void qconv_fused(
        const float* __restrict__ x,
        const float* __restrict__ w_enc,
        const float* __restrict__ a_rz,
        const float* __restrict__ b_ry,
        float* __restrict__ out) {
    // ---- per-block coefficient table (threads 0..53) ----
    // row t = f*27 + c*9 + q : [w*inv2pi, Rs.x,Rs.y,Rs.z, Rc.x,Rc.y,Rc.z, pad]
    __shared__ float stab[54 * 8];
    int tid = threadIdx.x;
    if (tid < 54) {
        int t = tid;
        int f = t / 27;
        int c = (t / 9) % 3;
        int q = t % 9;
        float ux = 1.f, uy = 0.f, uz = 0.f;   // image of e0
        float wx = 0.f, wy = 0.f, wz = 1.f;   // image of e2
#pragma unroll
        for (int l = 0; l < NL; ++l) {
            int ia = ((f * NC + c) * NL + l) * NQ + q;
            float sa, ca, sb, cb;
            __sincosf(a_rz[ia], &sa, &ca);
            __sincosf(b_ry[ia], &sb, &cb);
            float nx, ny, nz;
            nx = ux * ca - uy * sa; ny = ux * sa + uy * ca; ux = nx; uy = ny;
            nx = ux * cb + uz * sb; nz = -ux * sb + uz * cb; ux = nx; uz = nz;
            nx = wx * ca - wy * sa; ny = wx * sa + wy * ca; wx = nx; wy = ny;
            nx = wx * cb + wz * sb; nz = -wx * sb + wz * cb; wx = nx; wz = nz;
        }
        float* o = stab + t * 8;
        o[0] = w_enc[t] * INV2PI;
        o[1] = ux; o[2] = uy; o[3] = uz;
        o[4] = wx; o[5] = wy; o[6] = wz;
        o[7] = 0.f;
    }
    __syncthreads();

    // ---- per-thread setup ----
    int T0 = blockIdx.x * 256 + tid;          // < GTHREADS, no tail
    int grp = T0 / 18;                        // pixel-group (9 pixels along j)
    int q18 = T0 - grp * 18;                  // f*9 + q
    int f = (q18 >= 9) ? 1 : 0;
    int q = q18 - f * 9;
    int di = q / 3, dj = q - di * 3;

    float cw[3], sx[3], sy[3], sz[3], cx[3], cy[3], cz[3];
#pragma unroll
    for (int c = 0; c < 3; ++c) {
        const float* r = stab + (size_t)(f * 27 + c * 9 + q) * 8;
        float4 v0 = *reinterpret_cast<const float4*>(r);
        float4 v1 = *reinterpret_cast<const float4*>(r + 4);
        cw[c] = v0.x; sx[c] = v0.y; sy[c] = v0.z; sz[c] = v0.w;
        cx[c] = v1.x; cy[c] = v1.y; cz[c] = v1.z;
    }

    int b   = grp / (I0 * NGJ);
    int rem = grp - b * (I0 * NGJ);
    int i   = rem / NGJ;
    int j   = (rem - i * NGJ) * 9;            // group start column

    // one input base (row i+di, col j+dj), 9 pixels = 108 contiguous bytes
    const float* pin = x + ((size_t)((b * NH + i + di) * NW) + (j + dj)) * NC;
    // one output base; iter t stores at +t*216 bytes (imm-offset range)
    float* pout = out + (size_t)grp * 486 + q18 * 3;

    // ---- prefetch all 9 pixels (27 floats) up-front ----
    float p[27];
#pragma unroll
    for (int t = 0; t < 9; ++t) {
        f3 v = *reinterpret_cast<const f3*>(pin + t * 3);
        p[3 * t + 0] = v.x; p[3 * t + 1] = v.y; p[3 * t + 2] = v.z;
    }

    // ---- 9 × (compute + store), zero address math ----
#pragma unroll
    for (int t = 0; t < 9; ++t) {
        float a0 = 0.f, a1 = 0.f, a2 = 0.f;
#pragma unroll
        for (int c = 0; c < 3; ++c) {
            float xr = p[3 * t + c] * cw[c];
            float s  = __builtin_amdgcn_sinf(xr);
            float co = __builtin_amdgcn_cosf(xr);
            a0 = fmaf(sx[c], s, fmaf(cx[c], co, a0));
            a1 = fmaf(sy[c], s, fmaf(cy[c], co, a1));
            a2 = fmaf(sz[c], s, fmaf(cz[c], co, a2));
        }
        f3 r;
        r.x = fmaxf(a0, 0.f);
        r.y = fmaxf(a1, 0.f);
        r.z = fmaxf(a2, 0.f);
        *reinterpret_cast<f3*>(pout + t * 54) = r;
    }
}

extern "C" void kernel_launch(void* const* d_in, const int* in_sizes, int n_in,
                              void* d_out, int out_size, void* d_ws, size_t ws_size,
                              hipStream_t stream) {
    const float* x     = (const float*)d_in[0];
    const float* w_enc = (const float*)d_in[1];
    const float* a_rz  = (const float*)d_in[2];
    const float* b_ry  = (const float*)d_in[3];
    float* out = (float*)d_out;

    int block = 256;
    int grid = GTHREADS / block;   // 3969
    qconv_fused<<<grid, block, 0, stream>>>(x, w_enc, a_rz, b_ry, out);
}